// Round 1
// baseline (131.748 us; speedup 1.0000x reference)
//
#include <hip/hip_runtime.h>

// NCC via Parseval identity: Ex = DT*sum(x^2)+EPS (no FFT needed).
// x,y: [NT=4096][NCOL=3072] fp32 row-major (col = trace*3 + chan).
// Kernel 1: partial sums per column (atomics into 48KB ws).
// Kernel 2: cc per column + reduce to scalar.

#define NT 4096
#define NCOL 3072
#define NCOL4 (NCOL / 4)      // 768 float4 column-slots
#define TCHUNKS 128
#define TSTEPS (NT / TCHUNKS) // 32

__device__ __constant__ float c_dt = 0.001f;
__device__ __constant__ float c_eps = 1e-10f;

// ws layout (floats): sx2[NCOL] | sy2[NCOL] | sxy[NCOL] | amax_bits[NCOL] (as uint)
#define WS_FLOATS (4 * NCOL)

__global__ __launch_bounds__(256) void ncc_partial(const float* __restrict__ x,
                                                   const float* __restrict__ y,
                                                   float* __restrict__ ws) {
    const int g    = blockIdx.x % 3;   // column group (0..2)
    const int tch  = blockIdx.x / 3;   // time chunk (0..127)
    const int tid  = threadIdx.x;
    const int col4 = g * 256 + tid;    // float4 slot in [0, 768)
    const int j    = col4 * 4;         // first scalar column

    const float4* __restrict__ x4 = reinterpret_cast<const float4*>(x);
    const float4* __restrict__ y4 = reinterpret_cast<const float4*>(y);

    float sx2[4] = {0.f, 0.f, 0.f, 0.f};
    float sy2[4] = {0.f, 0.f, 0.f, 0.f};
    float sxy[4] = {0.f, 0.f, 0.f, 0.f};
    float amx[4] = {0.f, 0.f, 0.f, 0.f};

    const int t0 = tch * TSTEPS;
#pragma unroll 4
    for (int tt = 0; tt < TSTEPS; ++tt) {
        const int idx = (t0 + tt) * NCOL4 + col4;
        float4 xv = x4[idx];
        float4 yv = y4[idx];
        sx2[0] = fmaf(xv.x, xv.x, sx2[0]);
        sx2[1] = fmaf(xv.y, xv.y, sx2[1]);
        sx2[2] = fmaf(xv.z, xv.z, sx2[2]);
        sx2[3] = fmaf(xv.w, xv.w, sx2[3]);
        sy2[0] = fmaf(yv.x, yv.x, sy2[0]);
        sy2[1] = fmaf(yv.y, yv.y, sy2[1]);
        sy2[2] = fmaf(yv.z, yv.z, sy2[2]);
        sy2[3] = fmaf(yv.w, yv.w, sy2[3]);
        sxy[0] = fmaf(xv.x, yv.x, sxy[0]);
        sxy[1] = fmaf(xv.y, yv.y, sxy[1]);
        sxy[2] = fmaf(xv.z, yv.z, sxy[2]);
        sxy[3] = fmaf(xv.w, yv.w, sxy[3]);
        amx[0] = fmaxf(amx[0], fabsf(xv.x));
        amx[1] = fmaxf(amx[1], fabsf(xv.y));
        amx[2] = fmaxf(amx[2], fabsf(xv.z));
        amx[3] = fmaxf(amx[3], fabsf(xv.w));
    }

    float* __restrict__ sx2w = ws;
    float* __restrict__ sy2w = ws + NCOL;
    float* __restrict__ sxyw = ws + 2 * NCOL;
    unsigned int* __restrict__ amxw = reinterpret_cast<unsigned int*>(ws + 3 * NCOL);

#pragma unroll
    for (int k = 0; k < 4; ++k) {
        atomicAdd(&sx2w[j + k], sx2[k]);
        atomicAdd(&sy2w[j + k], sy2[k]);
        atomicAdd(&sxyw[j + k], sxy[k]);
        // |x| >= 0 so IEEE bits are monotone under unsigned compare
        atomicMax(&amxw[j + k], __float_as_uint(amx[k]));
    }
}

__global__ __launch_bounds__(1024) void ncc_final(const float* __restrict__ ws,
                                                  float* __restrict__ out) {
    const int tid = threadIdx.x;
    const float* __restrict__ sx2w = ws;
    const float* __restrict__ sy2w = ws + NCOL;
    const float* __restrict__ sxyw = ws + 2 * NCOL;
    const unsigned int* __restrict__ amxw =
        reinterpret_cast<const unsigned int*>(ws + 3 * NCOL);

    float acc = 0.f;
#pragma unroll
    for (int j = tid; j < NCOL; j += 1024) {
        float ex = fmaf(c_dt, sx2w[j], c_eps);
        float ey = fmaf(c_dt, sy2w[j], c_eps);
        float cc = sxyw[j] * rsqrtf(ex * ey);
        if (amxw[j] != 0u) acc += cc;
    }

    // wave64 butterfly reduce
#pragma unroll
    for (int off = 32; off > 0; off >>= 1)
        acc += __shfl_down(acc, off, 64);

    __shared__ float red[16];
    const int wave = tid >> 6;
    const int lane = tid & 63;
    if (lane == 0) red[wave] = acc;
    __syncthreads();
    if (wave == 0) {
        float v = (lane < 16) ? red[lane] : 0.f;
#pragma unroll
        for (int off = 8; off > 0; off >>= 1)
            v += __shfl_down(v, off, 64);
        if (lane == 0) out[0] = v;
    }
}

extern "C" void kernel_launch(void* const* d_in, const int* in_sizes, int n_in,
                              void* d_out, int out_size, void* d_ws, size_t ws_size,
                              hipStream_t stream) {
    const float* x = reinterpret_cast<const float*>(d_in[0]);
    const float* y = reinterpret_cast<const float*>(d_in[1]);
    float* out = reinterpret_cast<float*>(d_out);
    float* ws = reinterpret_cast<float*>(d_ws);

    // zero partial-sum workspace (0 bits == 0.0f and uint 0 for amax)
    hipMemsetAsync(ws, 0, WS_FLOATS * sizeof(float), stream);

    ncc_partial<<<dim3(3 * TCHUNKS), dim3(256), 0, stream>>>(x, y, ws);
    ncc_final<<<dim3(1), dim3(1024), 0, stream>>>(ws, out);
}

// Round 2
// 126.556 us; speedup vs baseline: 1.0410x; 1.0410x over previous
//
#include <hip/hip_runtime.h>

// NCC via Parseval: Ex = DT*sum(x^2)+EPS (no FFT). x,y: [NT=4096][NCOL=3072] fp32.
// mask(max|x|>0) == (sum x^2 > 0), so only 3 stats needed: sx2, sy2, sxy.
// Stage 1: per-time-chunk partial sums, NO atomics, coalesced float4 stores.
//   grid 768 = 3 blocks/CU uniform (256 chunks x 3 column-groups).
// Stage 2: 48 blocks reduce 256 chunks/column (4 threads/col + LDS), per-block sum.
// Stage 3: one wave sums 48 block partials -> out[0].

#define NT 4096
#define NCOL 3072
#define NCOL4 768          // float4 column-slots
#define CHUNKS 256
#define TSTEPS (NT / CHUNKS)   // 16

// ws layout: ps[3][CHUNKS][NCOL4] float4  (9.44 MB), then bsum[48] floats
#define PS_F4_PER_STAT (CHUNKS * NCOL4)
#define BSUM_OFFSET_BYTES (3 * PS_F4_PER_STAT * 16)

__global__ __launch_bounds__(256) void ncc_stage1(const float* __restrict__ x,
                                                  const float* __restrict__ y,
                                                  float4* __restrict__ ps) {
    const int bx   = blockIdx.x;
    const int g    = bx % 3;        // column group 0..2
    const int ch   = bx / 3;        // time chunk 0..255
    const int tid  = threadIdx.x;
    const int col4 = g * 256 + tid; // float4 slot in [0,768)

    const float4* __restrict__ x4 = reinterpret_cast<const float4*>(x);
    const float4* __restrict__ y4 = reinterpret_cast<const float4*>(y);

    float4 sx2 = {0.f, 0.f, 0.f, 0.f};
    float4 sy2 = {0.f, 0.f, 0.f, 0.f};
    float4 sxy = {0.f, 0.f, 0.f, 0.f};

    const int t0 = ch * TSTEPS;
#pragma unroll
    for (int tt = 0; tt < TSTEPS; ++tt) {
        const int idx = (t0 + tt) * NCOL4 + col4;
        float4 xv = x4[idx];
        float4 yv = y4[idx];
        sx2.x = fmaf(xv.x, xv.x, sx2.x);
        sx2.y = fmaf(xv.y, xv.y, sx2.y);
        sx2.z = fmaf(xv.z, xv.z, sx2.z);
        sx2.w = fmaf(xv.w, xv.w, sx2.w);
        sy2.x = fmaf(yv.x, yv.x, sy2.x);
        sy2.y = fmaf(yv.y, yv.y, sy2.y);
        sy2.z = fmaf(yv.z, yv.z, sy2.z);
        sy2.w = fmaf(yv.w, yv.w, sy2.w);
        sxy.x = fmaf(xv.x, yv.x, sxy.x);
        sxy.y = fmaf(xv.y, yv.y, sxy.y);
        sxy.z = fmaf(xv.z, yv.z, sxy.z);
        sxy.w = fmaf(xv.w, yv.w, sxy.w);
    }

    const int slot = ch * NCOL4 + col4;
    ps[0 * PS_F4_PER_STAT + slot] = sx2;
    ps[1 * PS_F4_PER_STAT + slot] = sy2;
    ps[2 * PS_F4_PER_STAT + slot] = sxy;
}

__global__ __launch_bounds__(256) void ncc_stage2(const float* __restrict__ ps,
                                                  float* __restrict__ bsum) {
    // ps as scalar floats: stat s, chunk c, col j -> ps[s*CHUNKS*NCOL + c*NCOL + j]
    const int b    = blockIdx.x;   // 0..47, owns 64 columns
    const int tid  = threadIdx.x;
    const int lane = tid & 63;
    const int q    = tid >> 6;     // chunk quarter 0..3
    const int j    = b * 64 + lane;

    float sx2 = 0.f, sy2 = 0.f, sxy = 0.f;
    const int c0 = q * (CHUNKS / 4);
#pragma unroll 4
    for (int c = c0; c < c0 + CHUNKS / 4; ++c) {
        sx2 += ps[0 * CHUNKS * NCOL + c * NCOL + j];
        sy2 += ps[1 * CHUNKS * NCOL + c * NCOL + j];
        sxy += ps[2 * CHUNKS * NCOL + c * NCOL + j];
    }

    __shared__ float red[3][4][64];
    red[0][q][lane] = sx2;
    red[1][q][lane] = sy2;
    red[2][q][lane] = sxy;
    __syncthreads();

    if (q == 0) {
        sx2 = red[0][0][lane] + red[0][1][lane] + red[0][2][lane] + red[0][3][lane];
        sy2 = red[1][0][lane] + red[1][1][lane] + red[1][2][lane] + red[1][3][lane];
        sxy = red[2][0][lane] + red[2][1][lane] + red[2][2][lane] + red[2][3][lane];
        float ex = fmaf(0.001f, sx2, 1e-10f);
        float ey = fmaf(0.001f, sy2, 1e-10f);
        float cc = (sx2 > 0.f) ? sxy * rsqrtf(ex * ey) : 0.f;
#pragma unroll
        for (int off = 32; off > 0; off >>= 1)
            cc += __shfl_down(cc, off, 64);
        if (lane == 0) bsum[b] = cc;
    }
}

__global__ __launch_bounds__(64) void ncc_stage3(const float* __restrict__ bsum,
                                                 float* __restrict__ out) {
    const int lane = threadIdx.x;
    float v = (lane < 48) ? bsum[lane] : 0.f;
#pragma unroll
    for (int off = 32; off > 0; off >>= 1)
        v += __shfl_down(v, off, 64);
    if (lane == 0) out[0] = v;
}

extern "C" void kernel_launch(void* const* d_in, const int* in_sizes, int n_in,
                              void* d_out, int out_size, void* d_ws, size_t ws_size,
                              hipStream_t stream) {
    const float* x = reinterpret_cast<const float*>(d_in[0]);
    const float* y = reinterpret_cast<const float*>(d_in[1]);
    float* out = reinterpret_cast<float*>(d_out);
    float4* ps = reinterpret_cast<float4*>(d_ws);
    float* bsum = reinterpret_cast<float*>(reinterpret_cast<char*>(d_ws) + BSUM_OFFSET_BYTES);

    ncc_stage1<<<dim3(3 * CHUNKS), dim3(256), 0, stream>>>(x, y, ps);
    ncc_stage2<<<dim3(48), dim3(256), 0, stream>>>(reinterpret_cast<const float*>(ps), bsum);
    ncc_stage3<<<dim3(1), dim3(64), 0, stream>>>(bsum, out);
}